// Round 9
// baseline (65.315 us; speedup 1.0000x reference)
//
#include <hip/hip_runtime.h>
#include <hip/hip_fp16.h>

#define NSTEPS 25            // atoms per sub-fragment
#define SUBF   (NSTEPS * 3)  // floats per sub-fragment = 75 (odd stride -> conflict-free LDS)
#define BLK    256
#define TILE_F (BLK * SUBF)  // 19200 floats per block tile

struct Xf { float m[12]; };  // x -> x @ R + t ; rows = m[0..8], t = m[9..11]

__device__ __forceinline__ Xf xf_identity() {
    Xf o;
    o.m[0]=1.f;o.m[1]=0.f;o.m[2]=0.f;
    o.m[3]=0.f;o.m[4]=1.f;o.m[5]=0.f;
    o.m[6]=0.f;o.m[7]=0.f;o.m[8]=1.f;
    o.m[9]=0.f;o.m[10]=0.f;o.m[11]=0.f;
    return o;
}

// (a∘b)(x) = (x @ Rb + tb) @ Ra + ta ; R = Rb*Ra, t = tb@Ra + ta
__device__ __forceinline__ Xf xf_compose(const Xf& a, const Xf& b) {
    Xf o;
#pragma unroll
    for (int i = 0; i < 3; ++i)
#pragma unroll
        for (int c = 0; c < 3; ++c)
            o.m[i*3+c] = b.m[i*3+0]*a.m[0+c] + b.m[i*3+1]*a.m[3+c] + b.m[i*3+2]*a.m[6+c];
#pragma unroll
    for (int c = 0; c < 3; ++c)
        o.m[9+c] = b.m[9+0]*a.m[0+c] + b.m[9+1]*a.m[3+c] + b.m[9+2]*a.m[6+c] + a.m[9+c];
    return o;
}

__device__ __forceinline__ void xf_store_g(float* p, const Xf& x) {
    float4* q = (float4*)p;
    q[0] = make_float4(x.m[0], x.m[1], x.m[2],  x.m[3]);
    q[1] = make_float4(x.m[4], x.m[5], x.m[6],  x.m[7]);
    q[2] = make_float4(x.m[8], x.m[9], x.m[10], x.m[11]);
}

__device__ __forceinline__ Xf xf_load_g(const float* p) {
    const float4* q = (const float4*)p;
    float4 a = q[0], b = q[1], c = q[2];
    Xf o;
    o.m[0]=a.x; o.m[1]=a.y; o.m[2]=a.z;  o.m[3]=a.w;
    o.m[4]=b.x; o.m[5]=b.y; o.m[6]=b.z;  o.m[7]=b.w;
    o.m[8]=c.x; o.m[9]=c.y; o.m[10]=c.z; o.m[11]=c.w;
    return o;
}

__device__ __forceinline__ Xf xf_shflup(const Xf& x, int d) {
    Xf o;
#pragma unroll
    for (int i = 0; i < 12; ++i) o.m[i] = __shfl_up(x.m[i], d, 64);
    return o;
}

// One NERF step. State: up = dir(B-A), u = dir(C-B), (cx,cy,cz) = C.
// frame rows = [u, cross(n,u), n], n = normalize(cross(up,u)).
// |D - C| == bond_length exactly, so u_next = d / bl (one rcp, no norm).
__device__ __forceinline__ void nerf_step(float bl, float ba, float ph,
    float& upx, float& upy, float& upz,
    float& ux,  float& uy,  float& uz,
    float& cx,  float& cy,  float& cz) {
    float sb, cb, sp, cp;
    __sincosf(ba, &sb, &cb);
    __sincosf(ph, &sp, &cp);
    float px = bl * cb;
    float rs = bl * sb;
    float py = cp * rs;
    float pz = sp * rs;
    float nx = upy*uz - upz*uy;
    float ny = upz*ux - upx*uz;
    float nz = upx*uy - upy*ux;
    float rin = __builtin_amdgcn_rsqf(nx*nx + ny*ny + nz*nz);
    nx *= rin; ny *= rin; nz *= rin;
    float mx = ny*uz - nz*uy;
    float my = nz*ux - nx*uz;
    float mz = nx*uy - ny*ux;
    float dx = px*ux + py*mx + pz*nx;
    float dy = px*uy + py*my + pz*ny;
    float dz = px*uz + py*mz + pz*nz;
    cx += dx; cy += dy; cz += dz;
    float ribl = __builtin_amdgcn_rcpf(bl);
    upx = ux; upy = uy; upz = uz;
    ux = dx*ribl; uy = dy*ribl; uz = dz*ribl;
}

#define UP0X (-0.5f)
#define UP0Y (-0.86602540378443865f)

__device__ __forceinline__ Xf make_T0(const float* __restrict__ mc) {
    float Ax=mc[0], Ay=mc[1], Az=mc[2];
    float Bx=mc[3], By=mc[4], Bz=mc[5];
    float Cx=mc[6], Cy=mc[7], Cz=mc[8];
    float bx = Cx-Bx, by = Cy-By, bz = Cz-Bz;
    float rb = __builtin_amdgcn_rsqf(bx*bx + by*by + bz*bz);
    bx *= rb; by *= rb; bz *= rb;
    float ex = Bx-Ax, ey = By-Ay, ez = Bz-Az;
    float nx = ey*bz - ez*by;
    float ny = ez*bx - ex*bz;
    float nz = ex*by - ey*bx;
    float rn = __builtin_amdgcn_rsqf(nx*nx + ny*ny + nz*nz);
    nx *= rn; ny *= rn; nz *= rn;
    float mx = ny*bz - nz*by;
    float my = nz*bx - nx*bz;
    float mz = nx*by - ny*bx;
    Xf T0;
    T0.m[0]=bx; T0.m[1]=by; T0.m[2]=bz;
    T0.m[3]=mx; T0.m[4]=my; T0.m[5]=mz;
    T0.m[6]=nx; T0.m[7]=ny; T0.m[8]=nz;
    T0.m[9]=Cx; T0.m[10]=Cy; T0.m[11]=Cz;
    return T0;
}

// K1: stage -> chain (points into LDS in place) -> block scan -> apply own thrEx
//     to own points -> fp16 half2 flush of block-local points + block link.
__global__ void __launch_bounds__(BLK, 2) k_links(
    const float* __restrict__ inner, __half* __restrict__ pts,
    float* __restrict__ blockLink, int nsub, int nfTot)
{
    __shared__ __align__(16) float data[TILE_F];   // 76800 B -> 2 blocks/CU
    __shared__ float sc[4 * 12];

    const int tid  = threadIdx.x;
    const int lane = tid & 63;
    const int wv   = tid >> 6;
    const int bid  = blockIdx.x;
    const int j    = bid * BLK + tid;
    const long base_f = (long)bid * TILE_F;
    int nf = nfTot - (int)base_f;
    if (nf > TILE_F) nf = TILE_F;

    {   // coalesced float4 staging
        const float4* src4 = (const float4*)(inner + base_f);
        float4* dst4 = (float4*)data;
        for (int i4 = tid; i4 < TILE_F / 4; i4 += BLK)
            if (i4 * 4 < nf) dst4[i4] = src4[i4];
    }
    __syncthreads();

    Xf L = xf_identity();
    if (j < nsub) {
        float upx=UP0X, upy=UP0Y, upz=0.f;
        float ux=1.f, uy=0.f, uz=0.f;
        float cx=0.f, cy=0.f, cz=0.f;
        float* s = data + tid * SUBF;
        for (int k = 0; k < NSTEPS; ++k) {
            float bl = s[3*k], ba = s[3*k+1], ph = s[3*k+2];
            nerf_step(bl, ba, ph, upx,upy,upz, ux,uy,uz, cx,cy,cz);
            s[3*k] = cx; s[3*k+1] = cy; s[3*k+2] = cz;   // local point
        }
        float nx = upy*uz - upz*uy;
        float ny = upz*ux - upx*uz;
        float nz = upx*uy - upy*ux;
        float rin = __builtin_amdgcn_rsqf(nx*nx + ny*ny + nz*nz);
        nx *= rin; ny *= rin; nz *= rin;
        float mx = ny*uz - nz*uy;
        float my = nz*ux - nx*uz;
        float mz = nx*uy - ny*ux;
        L.m[0]=ux; L.m[1]=uy; L.m[2]=uz;
        L.m[3]=mx; L.m[4]=my; L.m[5]=mz;
        L.m[6]=nx; L.m[7]=ny; L.m[8]=nz;
        L.m[9]=cx; L.m[10]=cy; L.m[11]=cz;
    }

    // wave inclusive Kogge-Stone
    Xf incl = L;
#pragma unroll
    for (int d = 1; d < 64; d <<= 1) {
        Xf p = xf_shflup(incl, d);
        if (lane >= d) incl = xf_compose(p, incl);
    }
    Xf laneEx = xf_shflup(incl, 1);
    if (lane == 0) laneEx = xf_identity();

    if (lane == 63) {
#pragma unroll
        for (int i = 0; i < 12; ++i) sc[wv*12 + i] = incl.m[i];
    }
    __syncthreads();

    Xf waveEx = xf_identity();
    for (int w = 0; w < wv; ++w) {
        Xf s;
#pragma unroll
        for (int i = 0; i < 12; ++i) s.m[i] = sc[w*12 + i];
        waveEx = xf_compose(waveEx, s);
    }
    Xf thrEx = xf_compose(waveEx, laneEx);   // exclusive prefix within block

    // apply thrEx to own 25 points -> block-local coordinates (in place)
    if (j < nsub) {
        float* s = data + tid * SUBF;
#pragma unroll
        for (int k = 0; k < NSTEPS; ++k) {
            float px = s[3*k], py = s[3*k+1], pz = s[3*k+2];
            s[3*k]   = px*thrEx.m[0] + py*thrEx.m[3] + pz*thrEx.m[6] + thrEx.m[9];
            s[3*k+1] = px*thrEx.m[1] + py*thrEx.m[4] + pz*thrEx.m[7] + thrEx.m[10];
            s[3*k+2] = px*thrEx.m[2] + py*thrEx.m[5] + pz*thrEx.m[8] + thrEx.m[11];
        }
    }

    if (tid == 0) {
        Xf agg;
#pragma unroll
        for (int i = 0; i < 12; ++i) agg.m[i] = sc[i];
        for (int w = 1; w < 4; ++w) {
            Xf s;
#pragma unroll
            for (int i = 0; i < 12; ++i) s.m[i] = sc[w*12 + i];
            agg = xf_compose(agg, s);
        }
        xf_store_g(blockLink + (size_t)bid * 12, agg);
    }
    __syncthreads();

    {   // fp16 half2 coalesced flush of block-local points
        __half2* dst2 = (__half2*)(pts + base_f);
        for (int i2 = tid; i2 < TILE_F / 2; i2 += BLK)
            if (2 * i2 < nf) {
                __half2 h;
                h.x = __float2half(data[2*i2]);
                h.y = __float2half(data[2*i2+1]);
                dst2[i2] = h;
            }
    }
}

// K2: single block scans NB block links (2/lane, NB<=512), folds in T0,
// writes global block prefixes + the 9 header floats.
__global__ void __launch_bounds__(BLK) k_scan(
    const float* __restrict__ blockLink, const float* __restrict__ mc,
    float* __restrict__ blockPrefix, float* __restrict__ out, int NB)
{
    __shared__ float sc[4 * 12];
    const int tid  = threadIdx.x;
    const int lane = tid & 63;
    const int wv   = tid >> 6;

    int i0 = 2*tid, i1 = 2*tid + 1;
    Xf e0 = (i0 < NB) ? xf_load_g(blockLink + (size_t)i0*12) : xf_identity();
    Xf e1 = (i1 < NB) ? xf_load_g(blockLink + (size_t)i1*12) : xf_identity();
    Xf pin = xf_compose(e0, e1);

    Xf inc2 = pin;
#pragma unroll
    for (int d = 1; d < 64; d <<= 1) {
        Xf p = xf_shflup(inc2, d);
        if (lane >= d) inc2 = xf_compose(p, inc2);
    }
    Xf pl = xf_shflup(inc2, 1);
    if (lane == 0) pl = xf_identity();
    if (lane == 63) {
#pragma unroll
        for (int i = 0; i < 12; ++i) sc[wv*12 + i] = inc2.m[i];
    }
    __syncthreads();
    Xf wex = xf_identity();
    for (int w = 0; w < wv; ++w) {
        Xf s;
#pragma unroll
        for (int i = 0; i < 12; ++i) s.m[i] = sc[w*12 + i];
        wex = xf_compose(wex, s);
    }

    Xf T0 = make_T0(mc);
    Xf g0 = xf_compose(xf_compose(T0, wex), pl);
    Xf g1 = xf_compose(g0, e0);
    if (i0 < NB) xf_store_g(blockPrefix + (size_t)i0*12, g0);
    if (i1 < NB) xf_store_g(blockPrefix + (size_t)i1*12, g1);

    if (tid == 0) {
#pragma unroll
        for (int i = 0; i < 9; ++i) out[i] = mc[i];
    }
}

// K3: pure streaming. Stage fp16 block-local points -> LDS; apply the
// block-uniform transform fused into the coalesced dword flush.
__global__ void __launch_bounds__(BLK, 4) k_emit(
    const __half* __restrict__ pts, const float* __restrict__ blockPrefix,
    float* __restrict__ out, int nfTot)
{
    __shared__ __align__(16) __half sdata[TILE_F];   // 38400 B -> 4 blocks/CU

    const int tid  = threadIdx.x;
    const int bid  = blockIdx.x;
    const long base_f = (long)bid * TILE_F;
    int nf = nfTot - (int)base_f;
    if (nf > TILE_F) nf = TILE_F;

    {   // coalesced staging: float4 = 8 halves per lane
        const float4* src4 = (const float4*)(pts + base_f);
        float4* dst4 = (float4*)sdata;
        for (int i8 = tid; i8 < TILE_F / 8; i8 += BLK)
            if (i8 * 8 < nf) dst4[i8] = src4[i8];
    }

    Xf T = xf_load_g(blockPrefix + (size_t)bid * 12);   // uniform per block
    __syncthreads();

    {   // fused transform + coalesced dword flush (out+9 is only 4B aligned)
        float* dst = out + 9 + base_f;
        for (int i = tid; i < nf; i += BLK) {
            int p = i / 3, c = i - 3 * p;        // mul-shift div
            float px = __half2float(sdata[3*p]);
            float py = __half2float(sdata[3*p+1]);
            float pz = __half2float(sdata[3*p+2]);
            dst[i] = px*T.m[0+c] + py*T.m[3+c] + pz*T.m[6+c] + T.m[9+c];
        }
    }
}

extern "C" void kernel_launch(void* const* d_in, const int* in_sizes, int n_in,
                              void* d_out, int out_size, void* d_ws, size_t ws_size,
                              hipStream_t stream) {
    const float* inner = (const float*)d_in[0];
    const float* mc    = (const float*)d_in[2];
    float* out = (float*)d_out;

    int nfTot = in_sizes[0];             // 9,000,000 floats
    int N     = nfTot / 3;               // 3,000,000 atoms
    int nsub  = N / NSTEPS;              // 120,000 sub-fragments
    int NB    = (nsub + BLK - 1) / BLK;  // 469 blocks (<= 512 for k_scan 2/lane)

    __half* pts        = (__half*)d_ws;                       // nfTot halves (18 MB)
    float* blockLink   = (float*)(pts + (size_t)nfTot);       // NB*12 floats
    float* blockPrefix = blockLink + (size_t)NB * 12;         // NB*12 floats

    k_links<<<NB, BLK, 0, stream>>>(inner, pts, blockLink, nsub, nfTot);
    k_scan<<<1, BLK, 0, stream>>>(blockLink, mc, blockPrefix, out, NB);
    k_emit<<<NB, BLK, 0, stream>>>(pts, blockPrefix, out, nfTot);
}

// Round 10
// 59.433 us; speedup vs baseline: 1.0990x; 1.0990x over previous
//
#include <hip/hip_runtime.h>

#define NSTEPS 25            // atoms per sub-fragment
#define SUBF   (NSTEPS * 3)  // floats per sub-fragment = 75
#define BLK    128           // threads per block; each thread runs TWO chains
#define PAIRS  (BLK * 2)     // sub-fragments per block = 256
#define TILE_F (PAIRS * SUBF) // 19200 floats per block tile (76.8 KB LDS)

struct Xf { float m[12]; };  // x -> x @ R + t ; rows = m[0..8], t = m[9..11]

__device__ __forceinline__ Xf xf_identity() {
    Xf o;
    o.m[0]=1.f;o.m[1]=0.f;o.m[2]=0.f;
    o.m[3]=0.f;o.m[4]=1.f;o.m[5]=0.f;
    o.m[6]=0.f;o.m[7]=0.f;o.m[8]=1.f;
    o.m[9]=0.f;o.m[10]=0.f;o.m[11]=0.f;
    return o;
}

// (a∘b)(x) = (x @ Rb + tb) @ Ra + ta ; R = Rb*Ra, t = tb@Ra + ta
__device__ __forceinline__ Xf xf_compose(const Xf& a, const Xf& b) {
    Xf o;
#pragma unroll
    for (int i = 0; i < 3; ++i)
#pragma unroll
        for (int c = 0; c < 3; ++c)
            o.m[i*3+c] = b.m[i*3+0]*a.m[0+c] + b.m[i*3+1]*a.m[3+c] + b.m[i*3+2]*a.m[6+c];
#pragma unroll
    for (int c = 0; c < 3; ++c)
        o.m[9+c] = b.m[9+0]*a.m[0+c] + b.m[9+1]*a.m[3+c] + b.m[9+2]*a.m[6+c] + a.m[9+c];
    return o;
}

__device__ __forceinline__ void xf_store_g(float* p, const Xf& x) {
    float4* q = (float4*)p;
    q[0] = make_float4(x.m[0], x.m[1], x.m[2],  x.m[3]);
    q[1] = make_float4(x.m[4], x.m[5], x.m[6],  x.m[7]);
    q[2] = make_float4(x.m[8], x.m[9], x.m[10], x.m[11]);
}

__device__ __forceinline__ Xf xf_load_g(const float* p) {
    const float4* q = (const float4*)p;
    float4 a = q[0], b = q[1], c = q[2];
    Xf o;
    o.m[0]=a.x; o.m[1]=a.y; o.m[2]=a.z;  o.m[3]=a.w;
    o.m[4]=b.x; o.m[5]=b.y; o.m[6]=b.z;  o.m[7]=b.w;
    o.m[8]=c.x; o.m[9]=c.y; o.m[10]=c.z; o.m[11]=c.w;
    return o;
}

__device__ __forceinline__ Xf xf_shflup(const Xf& x, int d) {
    Xf o;
#pragma unroll
    for (int i = 0; i < 12; ++i) o.m[i] = __shfl_up(x.m[i], d, 64);
    return o;
}

// One NERF step. State: up = dir(B-A), u = dir(C-B), (cx,cy,cz) = C.
__device__ __forceinline__ void nerf_step(float bl, float ba, float ph,
    float& upx, float& upy, float& upz,
    float& ux,  float& uy,  float& uz,
    float& cx,  float& cy,  float& cz) {
    float sb, cb, sp, cp;
    __sincosf(ba, &sb, &cb);
    __sincosf(ph, &sp, &cp);
    float px = bl * cb;
    float rs = bl * sb;
    float py = cp * rs;
    float pz = sp * rs;
    float nx = upy*uz - upz*uy;
    float ny = upz*ux - upx*uz;
    float nz = upx*uy - upy*ux;
    float rin = __builtin_amdgcn_rsqf(nx*nx + ny*ny + nz*nz);
    nx *= rin; ny *= rin; nz *= rin;
    float mx = ny*uz - nz*uy;
    float my = nz*ux - nx*uz;
    float mz = nx*uy - ny*ux;
    float dx = px*ux + py*mx + pz*nx;
    float dy = px*uy + py*my + pz*ny;
    float dz = px*uz + py*mz + pz*nz;
    cx += dx; cy += dy; cz += dz;
    float ribl = __builtin_amdgcn_rcpf(bl);
    upx = ux; upy = uy; upz = uz;
    ux = dx*ribl; uy = dy*ribl; uz = dz*ribl;
}

#define UP0X (-0.5f)
#define UP0Y (-0.86602540378443865f)

__device__ __forceinline__ Xf link_from_state(
    float upx, float upy, float upz,
    float ux,  float uy,  float uz,
    float cx,  float cy,  float cz) {
    float nx = upy*uz - upz*uy;
    float ny = upz*ux - upx*uz;
    float nz = upx*uy - upy*ux;
    float rin = __builtin_amdgcn_rsqf(nx*nx + ny*ny + nz*nz);
    nx *= rin; ny *= rin; nz *= rin;
    float mx = ny*uz - nz*uy;
    float my = nz*ux - nx*uz;
    float mz = nx*uy - ny*ux;
    Xf L;
    L.m[0]=ux; L.m[1]=uy; L.m[2]=uz;
    L.m[3]=mx; L.m[4]=my; L.m[5]=mz;
    L.m[6]=nx; L.m[7]=ny; L.m[8]=nz;
    L.m[9]=cx; L.m[10]=cy; L.m[11]=cz;
    return L;
}

__device__ __forceinline__ Xf make_T0(const float* __restrict__ mc) {
    float Ax=mc[0], Ay=mc[1], Az=mc[2];
    float Bx=mc[3], By=mc[4], Bz=mc[5];
    float Cx=mc[6], Cy=mc[7], Cz=mc[8];
    float bx = Cx-Bx, by = Cy-By, bz = Cz-Bz;
    float rb = __builtin_amdgcn_rsqf(bx*bx + by*by + bz*bz);
    bx *= rb; by *= rb; bz *= rb;
    float ex = Bx-Ax, ey = By-Ay, ez = Bz-Az;
    float nx = ey*bz - ez*by;
    float ny = ez*bx - ex*bz;
    float nz = ex*by - ey*bx;
    float rn = __builtin_amdgcn_rsqf(nx*nx + ny*ny + nz*nz);
    nx *= rn; ny *= rn; nz *= rn;
    float mx = ny*bz - nz*by;
    float my = nz*bx - nx*bz;
    float mz = nx*by - ny*bx;
    Xf T0;
    T0.m[0]=bx; T0.m[1]=by; T0.m[2]=bz;
    T0.m[3]=mx; T0.m[4]=my; T0.m[5]=mz;
    T0.m[6]=nx; T0.m[7]=ny; T0.m[8]=nz;
    T0.m[9]=Cx; T0.m[10]=Cy; T0.m[11]=Cz;
    return T0;
}

// K1: stage -> TWO interleaved chains per thread -> pair scan -> pair prefixes
//     (coalesced [i][a][npair] layout) + block link.
__global__ void __launch_bounds__(BLK, 1) k_links(
    const float* __restrict__ inner, float* __restrict__ thrPre,
    float* __restrict__ blockLink, int nsub, int nfTot)
{
    __shared__ __align__(16) float data[TILE_F];   // 76800 B -> 2 blocks/CU
    __shared__ float sc[2 * 12];

    const int tid  = threadIdx.x;
    const int lane = tid & 63;
    const int wv   = tid >> 6;          // 0..1
    const int bid  = blockIdx.x;
    const int jp   = bid * PAIRS + 2 * tid;   // first subfrag of this thread's pair
    const int npair = nsub >> 1;
    const int p    = bid * BLK + tid;         // pair index
    const long base_f = (long)bid * TILE_F;
    int nf = nfTot - (int)base_f;
    if (nf > TILE_F) nf = TILE_F;

    {   // coalesced float4 staging
        const float4* src4 = (const float4*)(inner + base_f);
        float4* dst4 = (float4*)data;
        for (int i4 = tid; i4 < TILE_F / 4; i4 += BLK)
            if (i4 * 4 < nf) dst4[i4] = src4[i4];
    }
    __syncthreads();

    const bool aA = (jp < nsub), aB = (jp + 1 < nsub);
    float Aux=1.f, Auy=0.f, Auz=0.f, Aupx=UP0X, Aupy=UP0Y, Aupz=0.f, Acx=0.f, Acy=0.f, Acz=0.f;
    float Bux=1.f, Buy=0.f, Buz=0.f, Bupx=UP0X, Bupy=UP0Y, Bupz=0.f, Bcx=0.f, Bcy=0.f, Bcz=0.f;
    const float* sA = data + (2 * tid) * SUBF;
    const float* sB = sA + SUBF;
    for (int k = 0; k < NSTEPS; ++k) {
        if (aA) nerf_step(sA[3*k], sA[3*k+1], sA[3*k+2],
                          Aupx,Aupy,Aupz, Aux,Auy,Auz, Acx,Acy,Acz);
        if (aB) nerf_step(sB[3*k], sB[3*k+1], sB[3*k+2],
                          Bupx,Bupy,Bupz, Bux,Buy,Buz, Bcx,Bcy,Bcz);
    }
    Xf LA = aA ? link_from_state(Aupx,Aupy,Aupz, Aux,Auy,Auz, Acx,Acy,Acz) : xf_identity();
    Xf LB = aB ? link_from_state(Bupx,Bupy,Bupz, Bux,Buy,Buz, Bcx,Bcy,Bcz) : xf_identity();
    Xf P  = xf_compose(LA, LB);   // pair link

    // wave inclusive Kogge-Stone over pair links
    Xf incl = P;
#pragma unroll
    for (int d = 1; d < 64; d <<= 1) {
        Xf q = xf_shflup(incl, d);
        if (lane >= d) incl = xf_compose(q, incl);
    }
    Xf laneEx = xf_shflup(incl, 1);
    if (lane == 0) laneEx = xf_identity();

    if (lane == 63) {
#pragma unroll
        for (int i = 0; i < 12; ++i) sc[wv*12 + i] = incl.m[i];
    }
    __syncthreads();

    Xf thrEx = laneEx;                 // pair-exclusive prefix within block
    if (wv == 1) {
        Xf s0;
#pragma unroll
        for (int i = 0; i < 12; ++i) s0.m[i] = sc[i];
        thrEx = xf_compose(s0, laneEx);
    }
    Xf ExA = thrEx;                    // prefix for subfrag 2t
    Xf ExB = xf_compose(thrEx, LA);    // prefix for subfrag 2t+1

    if (p < npair) {
#pragma unroll
        for (int i = 0; i < 12; ++i) {
            thrPre[((size_t)(2*i+0)) * npair + p] = ExA.m[i];
            thrPre[((size_t)(2*i+1)) * npair + p] = ExB.m[i];
        }
    }
    if (tid == 0) {
        Xf s0, s1;
#pragma unroll
        for (int i = 0; i < 12; ++i) { s0.m[i] = sc[i]; s1.m[i] = sc[12+i]; }
        xf_store_g(blockLink + (size_t)bid * 12, xf_compose(s0, s1));
    }
}

// K2: single block scans NB block links (2/lane, NB<=512), folds in T0,
// writes global block prefixes + the 9 header floats.
__global__ void __launch_bounds__(256) k_scan(
    const float* __restrict__ blockLink, const float* __restrict__ mc,
    float* __restrict__ blockPrefix, float* __restrict__ out, int NB)
{
    __shared__ float sc[4 * 12];
    const int tid  = threadIdx.x;
    const int lane = tid & 63;
    const int wv   = tid >> 6;

    int i0 = 2*tid, i1 = 2*tid + 1;
    Xf e0 = (i0 < NB) ? xf_load_g(blockLink + (size_t)i0*12) : xf_identity();
    Xf e1 = (i1 < NB) ? xf_load_g(blockLink + (size_t)i1*12) : xf_identity();
    Xf pin = xf_compose(e0, e1);

    Xf inc2 = pin;
#pragma unroll
    for (int d = 1; d < 64; d <<= 1) {
        Xf q = xf_shflup(inc2, d);
        if (lane >= d) inc2 = xf_compose(q, inc2);
    }
    Xf pl = xf_shflup(inc2, 1);
    if (lane == 0) pl = xf_identity();
    if (lane == 63) {
#pragma unroll
        for (int i = 0; i < 12; ++i) sc[wv*12 + i] = inc2.m[i];
    }
    __syncthreads();
    Xf wex = xf_identity();
    for (int w = 0; w < wv; ++w) {
        Xf s;
#pragma unroll
        for (int i = 0; i < 12; ++i) s.m[i] = sc[w*12 + i];
        wex = xf_compose(wex, s);
    }

    Xf T0 = make_T0(mc);
    Xf g0 = xf_compose(xf_compose(T0, wex), pl);
    Xf g1 = xf_compose(g0, e0);
    if (i0 < NB) xf_store_g(blockPrefix + (size_t)i0*12, g0);
    if (i1 < NB) xf_store_g(blockPrefix + (size_t)i1*12, g1);

    if (tid == 0) {
#pragma unroll
        for (int i = 0; i < 9; ++i) out[i] = mc[i];
    }
}

// K3: stage -> T = blockPrefix∘pairPrefix -> TWO interleaved transformed chains
//     per thread writing global points into LDS -> coalesced flush.
__global__ void __launch_bounds__(BLK, 1) k_emit(
    const float* __restrict__ inner, const float* __restrict__ thrPre,
    const float* __restrict__ blockPrefix, float* __restrict__ out,
    int nsub, int nfTot)
{
    __shared__ __align__(16) float data[TILE_F];

    const int tid  = threadIdx.x;
    const int bid  = blockIdx.x;
    const int jp   = bid * PAIRS + 2 * tid;
    const int npair = nsub >> 1;
    const int p    = bid * BLK + tid;
    const long base_f = (long)bid * TILE_F;
    int nf = nfTot - (int)base_f;
    if (nf > TILE_F) nf = TILE_F;

    {   // coalesced float4 staging
        const float4* src4 = (const float4*)(inner + base_f);
        float4* dst4 = (float4*)data;
        for (int i4 = tid; i4 < TILE_F / 4; i4 += BLK)
            if (i4 * 4 < nf) dst4[i4] = src4[i4];
    }
    __syncthreads();

    const bool aA = (jp < nsub), aB = (jp + 1 < nsub);
    if (p < npair) {
        Xf bp = xf_load_g(blockPrefix + (size_t)bid * 12);
        Xf teA, teB;
#pragma unroll
        for (int i = 0; i < 12; ++i) {
            teA.m[i] = thrPre[((size_t)(2*i+0)) * npair + p];
            teB.m[i] = thrPre[((size_t)(2*i+1)) * npair + p];
        }
        Xf TA = xf_compose(bp, teA);
        Xf TB = xf_compose(bp, teB);

        float Aux = TA.m[0], Auy = TA.m[1], Auz = TA.m[2];
        float Aupx = UP0X*TA.m[0] + UP0Y*TA.m[3];
        float Aupy = UP0X*TA.m[1] + UP0Y*TA.m[4];
        float Aupz = UP0X*TA.m[2] + UP0Y*TA.m[5];
        float Acx = TA.m[9], Acy = TA.m[10], Acz = TA.m[11];

        float Bux = TB.m[0], Buy = TB.m[1], Buz = TB.m[2];
        float Bupx = UP0X*TB.m[0] + UP0Y*TB.m[3];
        float Bupy = UP0X*TB.m[1] + UP0Y*TB.m[4];
        float Bupz = UP0X*TB.m[2] + UP0Y*TB.m[5];
        float Bcx = TB.m[9], Bcy = TB.m[10], Bcz = TB.m[11];

        float* sA = data + (2 * tid) * SUBF;
        float* sB = sA + SUBF;
        for (int k = 0; k < NSTEPS; ++k) {
            if (aA) {
                float bl = sA[3*k], ba = sA[3*k+1], ph = sA[3*k+2];
                nerf_step(bl, ba, ph, Aupx,Aupy,Aupz, Aux,Auy,Auz, Acx,Acy,Acz);
                sA[3*k] = Acx; sA[3*k+1] = Acy; sA[3*k+2] = Acz;
            }
            if (aB) {
                float bl = sB[3*k], ba = sB[3*k+1], ph = sB[3*k+2];
                nerf_step(bl, ba, ph, Bupx,Bupy,Bupz, Bux,Buy,Buz, Bcx,Bcy,Bcz);
                sB[3*k] = Bcx; sB[3*k+1] = Bcy; sB[3*k+2] = Bcz;
            }
        }
    }
    __syncthreads();

    {   // coalesced flush (out+9 breaks 16B alignment -> dword stores)
        float* dst = out + 9 + base_f;
        for (int i = tid; i < nf; i += BLK) dst[i] = data[i];
    }
}

extern "C" void kernel_launch(void* const* d_in, const int* in_sizes, int n_in,
                              void* d_out, int out_size, void* d_ws, size_t ws_size,
                              hipStream_t stream) {
    const float* inner = (const float*)d_in[0];
    const float* mc    = (const float*)d_in[2];
    float* out = (float*)d_out;

    int nfTot = in_sizes[0];               // 9,000,000 floats
    int N     = nfTot / 3;                 // 3,000,000 atoms
    int nsub  = N / NSTEPS;                // 120,000 sub-fragments
    int NB    = (nsub + PAIRS - 1) / PAIRS; // 469 blocks (<= 512 for k_scan 2/lane)

    float* thrPre      = (float*)d_ws;                   // 12*nsub floats ([2i+a][npair])
    float* blockLink   = thrPre + (size_t)12 * nsub;     // NB*12 floats
    float* blockPrefix = blockLink + (size_t)NB * 12;    // NB*12 floats

    k_links<<<NB, BLK, 0, stream>>>(inner, thrPre, blockLink, nsub, nfTot);
    k_scan<<<1, 256, 0, stream>>>(blockLink, mc, blockPrefix, out, NB);
    k_emit<<<NB, BLK, 0, stream>>>(inner, thrPre, blockPrefix, out, nsub, nfTot);
}